// Round 15
// baseline (1693.417 us; speedup 1.0000x reference)
//
#include <hip/hip_runtime.h>
#include <stdint.h>

#define S_LEN 2048
#define NHEAD 16

typedef short short8 __attribute__((ext_vector_type(8)));
typedef float f32x4 __attribute__((ext_vector_type(4)));
typedef unsigned short u16;

typedef __attribute__((address_space(1))) uint32_t AS1u32;
typedef __attribute__((address_space(3))) uint32_t AS3u32;

#define MFMA16(a, b, c) __builtin_amdgcn_mfma_f32_16x16x32_bf16((a), (b), (c), 0, 0, 0)

__device__ __forceinline__ void gload16(const void* g, void* l) {
  __builtin_amdgcn_global_load_lds((AS1u32*)g, (AS3u32*)l, 16, 0, 0);
}

__device__ __forceinline__ u16 f2bf(float f) {
  union { float f; uint32_t u; } c; c.f = f;
  return (u16)((c.u + 0x7fffu + ((c.u >> 16) & 1u)) >> 16);
}

// ---------------- prep: x -> bf16  +  weights -> bf16 transposed ----------------
__global__ __launch_bounds__(256) void prep_kernel(
    const float* __restrict__ x, u16* __restrict__ xb,
    const float* __restrict__ w0, const float* __restrict__ w1,
    const float* __restrict__ w2, const float* __restrict__ w3,
    u16* __restrict__ qkvT, u16* __restrict__ fcT) {
  __shared__ float t[32][33];
  int bid = blockIdx.x;
  if (bid < 8192) {
    size_t i = ((size_t)bid * 256 + threadIdx.x) * 4;
    f32x4 v = *(const f32x4*)(x + i);
    union { u16 h[4]; uint2 d; } o;
    o.h[0] = f2bf(v[0]); o.h[1] = f2bf(v[1]); o.h[2] = f2bf(v[2]); o.h[3] = f2bf(v[3]);
    *(uint2*)(xb + i) = o.d;
    return;
  }
  int r = bid - 8192;
  int z = r >> 10; r &= 1023;
  int bx = r & 31, by = r >> 5;
  const float* w = (z == 0) ? w0 : (z == 1) ? w1 : (z == 2) ? w2 : w3;
  u16* o = (z == 3) ? fcT : qkvT + (size_t)z * 1048576;
  float scale = (z == 0) ? 0.125f : 1.0f;
  int n0 = bx * 32, k0 = by * 32;
  int tx = threadIdx.x & 31, ty = threadIdx.x >> 5;
#pragma unroll
  for (int i = 0; i < 4; ++i) {
    int k = ty * 4 + i;
    t[k][tx] = w[(size_t)(k0 + k) * 1024 + n0 + tx];
  }
  __syncthreads();
#pragma unroll
  for (int i = 0; i < 4; ++i) {
    int n = ty * 4 + i;
    o[(size_t)(n0 + n) * 1024 + k0 + tx] = f2bf(t[tx][n] * scale);
  }
}

// ---------------- 128x128x(K=1024) bf16 GEMM, C = A * BT^T ----------------
__device__ __forceinline__ void gemm_stage(const char* Ab, const char* Bb, u16* As, u16* Bs,
                                           int m0, int n0, int kbyte, int tid) {
#pragma unroll
  for (int i = 0; i < 2; ++i) {
    int cid = i * 256 + tid;
    int row = cid >> 2, c = cid & 3;
    int off = kbyte + ((c ^ ((row >> 1) & 3)) << 4);
    gload16(Ab + (size_t)(m0 + row) * 2048 + off, (char*)As + i * 4096 + (tid & ~63) * 16);
    gload16(Bb + (size_t)(n0 + row) * 2048 + off, (char*)Bs + i * 4096 + (tid & ~63) * 16);
  }
}

__global__ __launch_bounds__(256) void gemm_bt_kernel(
    const u16* __restrict__ A, const u16* __restrict__ BT,
    void* __restrict__ out, void* __restrict__ outv, int mode) {
  __shared__ u16 sh[128 * 128];
  u16* As = sh;
  u16* Bs = sh + 4096;
  const int tid = threadIdx.x;
  const int lane = tid & 63, wv = tid >> 6;
  const int l15 = lane & 15, h16 = lane >> 4;
  const int wr = wv >> 1, wc = wv & 1;
  const int m0 = blockIdx.x * 128, n0 = blockIdx.y * 128;
  const char* Ab = (const char*)A;
  const char* Bb = (const char*)BT;

  f32x4 acc[4][4];
#pragma unroll
  for (int i = 0; i < 4; ++i)
#pragma unroll
    for (int j = 0; j < 4; ++j) acc[i][j] = (f32x4){0.f, 0.f, 0.f, 0.f};

  gemm_stage(Ab, Bb, As, Bs, m0, n0, 0, tid);
  for (int kt = 0; kt < 32; ++kt) {
    __syncthreads();
    short8 a[4], b[4];
#pragma unroll
    for (int mf = 0; mf < 4; ++mf) {
      int row = wr * 64 + mf * 16 + l15;
      a[mf] = *(const short8*)((const char*)As + row * 64 + ((h16 ^ ((row >> 1) & 3)) << 4));
    }
#pragma unroll
    for (int nf = 0; nf < 4; ++nf) {
      int row = wc * 64 + nf * 16 + l15;
      b[nf] = *(const short8*)((const char*)Bs + row * 64 + ((h16 ^ ((row >> 1) & 3)) << 4));
    }
#pragma unroll
    for (int mf = 0; mf < 4; ++mf)
#pragma unroll
      for (int nf = 0; nf < 4; ++nf)
        acc[mf][nf] = MFMA16(a[mf], b[nf], acc[mf][nf]);
    __syncthreads();
    if (kt + 1 < 32) gemm_stage(Ab, Bb, As, Bs, m0, n0, (kt + 1) * 64, tid);
  }

  if (mode == 0 && n0 < 2048) {
    u16* o = (u16*)out;
#pragma unroll
    for (int mf = 0; mf < 4; ++mf)
#pragma unroll
      for (int nf = 0; nf < 4; ++nf)
#pragma unroll
        for (int r = 0; r < 4; ++r) {
          int row = wr * 64 + mf * 16 + 4 * h16 + r;
          int col = wc * 64 + nf * 16 + l15;
          *(u16*)((char*)sh + row * 256 + (((col >> 3) ^ (row & 7)) << 4) + (col & 7) * 2) =
              f2bf(acc[mf][nf][r]);
        }
    __syncthreads();
    int row = tid >> 1, hf = tid & 1;
    int m = m0 + row;
    int bb = m >> 11, s = m & 2047;
    int n_base = n0 + hf * 64;
    int z = n_base >> 10, nn = n_base & 1023, hh = nn >> 6;
    u16* dst = o + (size_t)z * 8388608 + (((size_t)(bb * NHEAD + hh) * S_LEN + s) << 6);
#pragma unroll
    for (int i = 0; i < 8; ++i) {
      int ch = hf * 8 + i;
      short8 v = *(const short8*)((const char*)sh + row * 256 + ((ch ^ (row & 7)) << 4));
      *(short8*)(dst + i * 8) = v;
    }
  } else if (mode == 0) {
    u16* o = (u16*)outv;
#pragma unroll
    for (int mf = 0; mf < 4; ++mf)
#pragma unroll
      for (int nf = 0; nf < 4; ++nf)
#pragma unroll
        for (int r = 0; r < 4; ++r) {
          int row = wr * 64 + mf * 16 + 4 * h16 + r;      // s-local
          int col = wc * 64 + nf * 16 + l15;              // n-local
          *(u16*)((char*)sh + col * 256 + (((row >> 3) ^ (col & 7)) << 4) + (row & 7) * 2) =
              f2bf(acc[mf][nf][r]);
        }
    __syncthreads();
    int col = tid >> 1, half = tid & 1;
    int bb = m0 >> 11, s0 = (m0 & 2047) + half * 64;
    int nn = n0 - 2048 + col;
    int hh = nn >> 6, dv = nn & 63;
    u16* dst = o + ((size_t)(bb * NHEAD + hh) * 64 + dv) * S_LEN + s0;
    const char* base = (const char*)sh + col * 256;
#pragma unroll
    for (int i = 0; i < 8; ++i) {
      int ch = (half * 8 + i) ^ (col & 7);
      *(short8*)(dst + i * 8) = *(const short8*)(base + (ch << 4));
    }
  } else {
    float* o = (float*)out;
#pragma unroll
    for (int mf = 0; mf < 4; ++mf)
#pragma unroll
      for (int nf = 0; nf < 4; ++nf)
#pragma unroll
        for (int r = 0; r < 4; ++r) {
          int m = m0 + wr * 64 + mf * 16 + 4 * h16 + r;
          int n = n0 + wc * 64 + nf * 16 + l15;
          o[(size_t)m * 1024 + n] = acc[mf][nf][r];
        }
  }
}

// ---------------- attention staging helpers ----------------
__device__ __forceinline__ void stage_qk(const char* base, int row0, u16* dst, int tid) {
#pragma unroll
  for (int i = 0; i < 2; ++i) {
    int cid = i * 512 + tid;
    int row = cid >> 3, c = cid & 7;
    gload16(base + (size_t)(row0 + row) * 128 + ((c ^ (row & 7)) << 4),
            (char*)dst + i * 8192 + (tid & ~63) * 16);
  }
}
__device__ __forceinline__ void stage_v(const char* Vb, int kv0, u16* dst, int tid) {
#pragma unroll
  for (int i = 0; i < 2; ++i) {
    int cid = i * 512 + tid;
    int row = cid >> 4, c = cid & 15;
    gload16(Vb + (size_t)row * 4096 + (size_t)kv0 * 2 + ((c ^ (row & 7)) << 4),
            (char*)dst + i * 8192 + (tid & ~63) * 16);
  }
}

template <int PRIO>
__device__ __forceinline__ void qk_tile(const char* Kc, const short8* qf,
                                        f32x4* sc, int l15, int h16) {
#pragma unroll
  for (int nf = 0; nf < 8; ++nf) sc[nf] = (f32x4){0.f, 0.f, 0.f, 0.f};
  if (PRIO) __builtin_amdgcn_s_setprio(1);
#pragma unroll
  for (int ks = 0; ks < 2; ++ks)
#pragma unroll
    for (int nf = 0; nf < 8; ++nf) {
      int row = nf * 16 + l15;
      short8 kb = *(const short8*)(Kc + row * 128 + (((ks * 4 + h16) ^ (row & 7)) << 4));
      sc[nf] = MFMA16(qf[ks], kb, sc[nf]);
    }
  if (PRIO) __builtin_amdgcn_s_setprio(0);
}

// ---------------- fused attention: denom prologue + emit, one (qt,bh) ----------------
template <int PRIO>
__device__ __forceinline__ void attn_one(
    const u16* __restrict__ Q, const u16* __restrict__ K, const u16* __restrict__ VT,
    float* __restrict__ attn, u16* __restrict__ ctx, int qt, int bh, int tid,
    u16 (*Ks)[128 * 64], u16* Vs, u16* Ps) {
  const int lane = tid & 63, wv = tid >> 6;
  const int l15 = lane & 15, h16 = lane >> 4;
  const int w16 = wv * 16;
  const int q0 = qt * 128;
  const char* Qb = (const char*)(Q + (size_t)bh * S_LEN * 64);
  const char* Kb = (const char*)(K + (size_t)bh * S_LEN * 64);
  const char* Vb = (const char*)(VT + (size_t)bh * 64 * S_LEN);
  float* attb = attn + (size_t)bh * S_LEN * S_LEN;

  stage_qk(Qb, q0, Ps, tid);           // Q parked in Ps region
  stage_qk(Kb, q0, Ks[0], tid);        // K[qt] (pass 1 runs descending)
  __syncthreads();
  short8 qf[2];
  {
    int row = w16 + l15;
    qf[0] = *(const short8*)((const char*)Ps + row * 128 + ((h16 ^ (row & 7)) << 4));
    qf[1] = *(const short8*)((const char*)Ps + row * 128 + (((4 + h16) ^ (row & 7)) << 4));
  }
  __syncthreads();

  // ---- pass 1: denominators (t = qt .. 0, K double-buffered) ----
  float lsum[4] = {0.f, 0.f, 0.f, 0.f};
  int cur = 0;
  for (int t = qt; t >= 0; --t) {
    if (t > 0) stage_qk(Kb, (t - 1) * 128, Ks[cur ^ 1], tid);
    f32x4 sc[8];
    qk_tile<PRIO>((const char*)Ks[cur], qf, sc, l15, h16);
    if (t == qt) {
#pragma unroll
      for (int nf = 0; nf < 8; ++nf)
#pragma unroll
        for (int r = 0; r < 4; ++r)
          if (nf * 16 + l15 > w16 + 4 * h16 + r) sc[nf][r] = -1e30f;
    }
#pragma unroll
    for (int nf = 0; nf < 8; ++nf)
#pragma unroll
      for (int r = 0; r < 4; ++r) lsum[r] += __expf(sc[nf][r]);
    __syncthreads();
    cur ^= 1;
  }
  cur ^= 1;                            // Ks[cur] holds K tile t=0
  f32x4 ri;
#pragma unroll
  for (int r = 0; r < 4; ++r) {
    float v = lsum[r];
    v += __shfl_xor(v, 1);
    v += __shfl_xor(v, 2);
    v += __shfl_xor(v, 4);
    v += __shfl_xor(v, 8);
    ri[r] = 1.0f / v;
  }

  // ---- pass 2: emit (t = 0 .. qt) ----
  f32x4 cacc[4];
#pragma unroll
  for (int nf = 0; nf < 4; ++nf) cacc[nf] = (f32x4){0.f, 0.f, 0.f, 0.f};

  for (int t = 0; t <= qt; ++t) {
    const int kv0 = t * 128;
    stage_v(Vb, kv0, Vs, tid);         // in flight during QK phase
    f32x4 sc[8];
    qk_tile<PRIO>((const char*)Ks[cur], qf, sc, l15, h16);
    if (t == qt) {
#pragma unroll
      for (int nf = 0; nf < 8; ++nf)
#pragma unroll
        for (int r = 0; r < 4; ++r)
          if (nf * 16 + l15 > w16 + 4 * h16 + r) sc[nf][r] = -1e30f;
    }
    // exp -> P(bf16) to LDS for PV, and DIRECT f32 attn store from registers.
    {
      float* arow = attb + (size_t)(q0 + w16 + 4 * h16) * S_LEN + kv0 + l15;
#pragma unroll
      for (int nf = 0; nf < 8; ++nf)
#pragma unroll
        for (int r = 0; r < 4; ++r) {
          float p = __expf(sc[nf][r]) * ri[r];
          int rowL = w16 + 4 * h16 + r;
          int chunk = 2 * nf + (l15 >> 3);
          *(u16*)((char*)Ps + rowL * 256 + ((chunk ^ (rowL & 7)) << 4) + (l15 & 7) * 2) = f2bf(p);
          arow[(size_t)r * S_LEN + nf * 16] = p;
        }
    }
    __syncthreads();                   // V[t] ready, P visible (attn stores drain to L2)
    if (t < qt) stage_qk(Kb, kv0 + 128, Ks[cur ^ 1], tid);  // in flight during PV
    // PV
    if (PRIO) __builtin_amdgcn_s_setprio(1);
#pragma unroll
    for (int ks = 0; ks < 4; ++ks) {
      int rowP = w16 + l15;
      short8 pa = *(const short8*)((const char*)Ps + rowP * 256 + (((ks * 4 + h16) ^ (rowP & 7)) << 4));
#pragma unroll
      for (int nf = 0; nf < 4; ++nf) {
        int rowV = nf * 16 + l15;
        short8 vbf = *(const short8*)((const char*)Vs + rowV * 256 + (((ks * 4 + h16) ^ (rowV & 7)) << 4));
        cacc[nf] = MFMA16(pa, vbf, cacc[nf]);
      }
    }
    if (PRIO) __builtin_amdgcn_s_setprio(0);
    __syncthreads();                   // Ps/Vs reuse; K[t+1] drained
    cur ^= 1;
  }

  // upper-triangle tiles are exactly zero
  for (int kvt = qt + 1; kvt < 16; ++kvt) {
    const int kv0 = kvt * 128;
    int row = tid >> 2, sub = tid & 3;
    float* arow = attb + (size_t)(q0 + row) * S_LEN + kv0;
    f32x4 z = {0.f, 0.f, 0.f, 0.f};
#pragma unroll
    for (int c8 = 0; c8 < 4; ++c8) {
      int chunk = sub + 4 * c8;
      *(f32x4*)(arow + chunk * 8) = z;
      *(f32x4*)(arow + chunk * 8 + 4) = z;
    }
  }

  // context store (B*S, H*64) bf16
  {
    int b = bh >> 4, hh = bh & 15;
#pragma unroll
    for (int nf = 0; nf < 4; ++nf)
#pragma unroll
      for (int r = 0; r < 4; ++r) {
        int qrow = q0 + w16 + 4 * h16 + r;
        ctx[((size_t)b * S_LEN + qrow) * 1024 + hh * 64 + nf * 16 + l15] = f2bf(cacc[nf][r]);
      }
  }
}

// 1-D grid 512, XCD-clustered. reps>1 only for profiling dispatches (idempotent).
template <int PRIO>
__global__ __launch_bounds__(512) void attn2_kernel(
    const u16* __restrict__ Q, const u16* __restrict__ K, const u16* __restrict__ VT,
    float* __restrict__ attn, u16* __restrict__ ctx, int reps) {
  __shared__ u16 Ks[2][128 * 64];
  __shared__ u16 Vs[64 * 128];
  __shared__ u16 Ps[128 * 128];
  const int tid = threadIdx.x;
  const int w = blockIdx.x;
  const int bx = (w >> 3) & 7;
  const int bh = (w & 7) + ((w >> 6) << 3);
  for (int rep = 0; rep < reps; ++rep) {
    attn_one<PRIO>(Q, K, VT, attn, ctx, 15 - bx, bh, tid, Ks, Vs, Ps);
    attn_one<PRIO>(Q, K, VT, attn, ctx, bx, bh, tid, Ks, Vs, Ps);
  }
}

// ---------------- residual + layernorm (in-place on proj) ----------------
__global__ __launch_bounds__(256) void ln_kernel(float* __restrict__ io,
                                                 const float* __restrict__ x,
                                                 const float* __restrict__ gamma,
                                                 const float* __restrict__ beta) {
  int row = blockIdx.x, tid = threadIdx.x;
  size_t base = (size_t)row * 1024 + tid * 4;
  f32x4 p = *(const f32x4*)(io + base);
  f32x4 xv = *(const f32x4*)(x + base);
  f32x4 y;
  float s1 = 0.f, s2 = 0.f;
#pragma unroll
  for (int j = 0; j < 4; ++j) {
    y[j] = p[j] + xv[j];
    s1 += y[j];
    s2 += y[j] * y[j];
  }
#pragma unroll
  for (int off = 1; off <= 32; off <<= 1) {
    s1 += __shfl_xor(s1, off);
    s2 += __shfl_xor(s2, off);
  }
  __shared__ float r1[4], r2[4];
  int w = tid >> 6;
  if ((tid & 63) == 0) { r1[w] = s1; r2[w] = s2; }
  __syncthreads();
  float S1 = r1[0] + r1[1] + r1[2] + r1[3];
  float S2 = r2[0] + r2[1] + r2[2] + r2[3];
  float mu = S1 * (1.f / 1024.f);
  float var = S2 * (1.f / 1024.f) - mu * mu;
  float rs = rsqrtf(var + 1e-5f);
  f32x4 g = *(const f32x4*)(gamma + tid * 4);
  f32x4 bt = *(const f32x4*)(beta + tid * 4);
  f32x4 o;
#pragma unroll
  for (int j = 0; j < 4; ++j) o[j] = (y[j] - mu) * rs * g[j] + bt[j];
  *(f32x4*)(io + base) = o;
}

extern "C" void kernel_launch(void* const* d_in, const int* in_sizes, int n_in,
                              void* d_out, int out_size, void* d_ws, size_t ws_size,
                              hipStream_t stream) {
  (void)in_sizes; (void)n_in; (void)out_size; (void)ws_size;
  const float* x = (const float*)d_in[0];
  // d_in[1] = attention_mask: deterministic causal, applied analytically, never read.
  const float* wq = (const float*)d_in[2];
  const float* wk = (const float*)d_in[3];
  const float* wv = (const float*)d_in[4];
  const float* wfc = (const float*)d_in[5];
  const float* gamma = (const float*)d_in[6];
  const float* beta = (const float*)d_in[7];

  char* ws = (char*)d_ws;
  u16* xb = (u16*)ws;
  u16* wqkvT = (u16*)(ws + (16u << 20));
  u16* wfcT = (u16*)(ws + (22u << 20));
  u16* qkb = (u16*)(ws + (24u << 20));
  u16* qb = qkb;
  u16* kb = qkb + (size_t)8388608;
  u16* vT = (u16*)(ws + (56u << 20));
  u16* ctx = xb;

  float* outp = (float*)d_out;
  float* attnp = outp + (size_t)4 * 2048 * 1024;

  prep_kernel<<<12288, 256, 0, stream>>>(x, xb, wq, wk, wv, wfc, wqkvT, wfcT);
  gemm_bt_kernel<<<dim3(64, 24), 256, 0, stream>>>(xb, wqkvT, qkb, vT, 0);
  attn2_kernel<0><<<512, 512, 0, stream>>>(qb, kb, vT, attnp, ctx, 1);
  gemm_bt_kernel<<<dim3(64, 8), 256, 0, stream>>>(ctx, wfcT, outp, nullptr, 1);
  ln_kernel<<<8192, 256, 0, stream>>>(outp, x, gamma, beta);
  // PROFILING A/B (idempotent rewrites of attnp/ctx with identical values; outp
  // untouched, so final buffers remain correct). Surfaces both variants in the
  // rocprof top-5 with PMCs. Remove next round once counters are read.
  attn2_kernel<0><<<512, 512, 0, stream>>>(qb, kb, vT, attnp, ctx, 2);  // A: clean
  attn2_kernel<1><<<512, 512, 0, stream>>>(qb, kb, vT, attnp, ctx, 2);  // B: setprio
}

// Round 16
// 546.988 us; speedup vs baseline: 3.0959x; 3.0959x over previous
//
#include <hip/hip_runtime.h>
#include <stdint.h>

#define S_LEN 2048
#define NHEAD 16

typedef short short8 __attribute__((ext_vector_type(8)));
typedef float f32x4 __attribute__((ext_vector_type(4)));
typedef unsigned short u16;

typedef __attribute__((address_space(1))) uint32_t AS1u32;
typedef __attribute__((address_space(3))) uint32_t AS3u32;

#define MFMA16(a, b, c) __builtin_amdgcn_mfma_f32_16x16x32_bf16((a), (b), (c), 0, 0, 0)

__device__ __forceinline__ void gload16(const void* g, void* l) {
  __builtin_amdgcn_global_load_lds((AS1u32*)g, (AS3u32*)l, 16, 0, 0);
}

__device__ __forceinline__ u16 f2bf(float f) {
  union { float f; uint32_t u; } c; c.f = f;
  return (u16)((c.u + 0x7fffu + ((c.u >> 16) & 1u)) >> 16);
}

// ---------------- prep: x -> bf16  +  weights -> bf16 transposed ----------------
__global__ __launch_bounds__(256) void prep_kernel(
    const float* __restrict__ x, u16* __restrict__ xb,
    const float* __restrict__ w0, const float* __restrict__ w1,
    const float* __restrict__ w2, const float* __restrict__ w3,
    u16* __restrict__ qkvT, u16* __restrict__ fcT) {
  __shared__ float t[32][33];
  int bid = blockIdx.x;
  if (bid < 8192) {
    size_t i = ((size_t)bid * 256 + threadIdx.x) * 4;
    f32x4 v = *(const f32x4*)(x + i);
    union { u16 h[4]; uint2 d; } o;
    o.h[0] = f2bf(v[0]); o.h[1] = f2bf(v[1]); o.h[2] = f2bf(v[2]); o.h[3] = f2bf(v[3]);
    *(uint2*)(xb + i) = o.d;
    return;
  }
  int r = bid - 8192;
  int z = r >> 10; r &= 1023;
  int bx = r & 31, by = r >> 5;
  const float* w = (z == 0) ? w0 : (z == 1) ? w1 : (z == 2) ? w2 : w3;
  u16* o = (z == 3) ? fcT : qkvT + (size_t)z * 1048576;
  float scale = (z == 0) ? 0.125f : 1.0f;
  int n0 = bx * 32, k0 = by * 32;
  int tx = threadIdx.x & 31, ty = threadIdx.x >> 5;
#pragma unroll
  for (int i = 0; i < 4; ++i) {
    int k = ty * 4 + i;
    t[k][tx] = w[(size_t)(k0 + k) * 1024 + n0 + tx];
  }
  __syncthreads();
#pragma unroll
  for (int i = 0; i < 4; ++i) {
    int n = ty * 4 + i;
    o[(size_t)(n0 + n) * 1024 + k0 + tx] = f2bf(t[tx][n] * scale);
  }
}

// ---------------- 128x128x(K=1024) bf16 GEMM, C = A * BT^T ----------------
__device__ __forceinline__ void gemm_stage(const char* Ab, const char* Bb, u16* As, u16* Bs,
                                           int m0, int n0, int kbyte, int tid) {
#pragma unroll
  for (int i = 0; i < 2; ++i) {
    int cid = i * 256 + tid;
    int row = cid >> 2, c = cid & 3;
    int off = kbyte + ((c ^ ((row >> 1) & 3)) << 4);
    gload16(Ab + (size_t)(m0 + row) * 2048 + off, (char*)As + i * 4096 + (tid & ~63) * 16);
    gload16(Bb + (size_t)(n0 + row) * 2048 + off, (char*)Bs + i * 4096 + (tid & ~63) * 16);
  }
}

__global__ __launch_bounds__(256) void gemm_bt_kernel(
    const u16* __restrict__ A, const u16* __restrict__ BT,
    void* __restrict__ out, void* __restrict__ outv, int mode) {
  __shared__ u16 sh[128 * 128];
  u16* As = sh;
  u16* Bs = sh + 4096;
  const int tid = threadIdx.x;
  const int lane = tid & 63, wv = tid >> 6;
  const int l15 = lane & 15, h16 = lane >> 4;
  const int wr = wv >> 1, wc = wv & 1;
  const int m0 = blockIdx.x * 128, n0 = blockIdx.y * 128;
  const char* Ab = (const char*)A;
  const char* Bb = (const char*)BT;

  f32x4 acc[4][4];
#pragma unroll
  for (int i = 0; i < 4; ++i)
#pragma unroll
    for (int j = 0; j < 4; ++j) acc[i][j] = (f32x4){0.f, 0.f, 0.f, 0.f};

  gemm_stage(Ab, Bb, As, Bs, m0, n0, 0, tid);
  for (int kt = 0; kt < 32; ++kt) {
    __syncthreads();
    short8 a[4], b[4];
#pragma unroll
    for (int mf = 0; mf < 4; ++mf) {
      int row = wr * 64 + mf * 16 + l15;
      a[mf] = *(const short8*)((const char*)As + row * 64 + ((h16 ^ ((row >> 1) & 3)) << 4));
    }
#pragma unroll
    for (int nf = 0; nf < 4; ++nf) {
      int row = wc * 64 + nf * 16 + l15;
      b[nf] = *(const short8*)((const char*)Bs + row * 64 + ((h16 ^ ((row >> 1) & 3)) << 4));
    }
#pragma unroll
    for (int mf = 0; mf < 4; ++mf)
#pragma unroll
      for (int nf = 0; nf < 4; ++nf)
        acc[mf][nf] = MFMA16(a[mf], b[nf], acc[mf][nf]);
    __syncthreads();
    if (kt + 1 < 32) gemm_stage(Ab, Bb, As, Bs, m0, n0, (kt + 1) * 64, tid);
  }

  if (mode == 0 && n0 < 2048) {
    u16* o = (u16*)out;
#pragma unroll
    for (int mf = 0; mf < 4; ++mf)
#pragma unroll
      for (int nf = 0; nf < 4; ++nf)
#pragma unroll
        for (int r = 0; r < 4; ++r) {
          int row = wr * 64 + mf * 16 + 4 * h16 + r;
          int col = wc * 64 + nf * 16 + l15;
          *(u16*)((char*)sh + row * 256 + (((col >> 3) ^ (row & 7)) << 4) + (col & 7) * 2) =
              f2bf(acc[mf][nf][r]);
        }
    __syncthreads();
    int row = tid >> 1, hf = tid & 1;
    int m = m0 + row;
    int bb = m >> 11, s = m & 2047;
    int n_base = n0 + hf * 64;
    int z = n_base >> 10, nn = n_base & 1023, hh = nn >> 6;
    u16* dst = o + (size_t)z * 8388608 + (((size_t)(bb * NHEAD + hh) * S_LEN + s) << 6);
#pragma unroll
    for (int i = 0; i < 8; ++i) {
      int ch = hf * 8 + i;
      short8 v = *(const short8*)((const char*)sh + row * 256 + ((ch ^ (row & 7)) << 4));
      *(short8*)(dst + i * 8) = v;
    }
  } else if (mode == 0) {
    u16* o = (u16*)outv;
#pragma unroll
    for (int mf = 0; mf < 4; ++mf)
#pragma unroll
      for (int nf = 0; nf < 4; ++nf)
#pragma unroll
        for (int r = 0; r < 4; ++r) {
          int row = wr * 64 + mf * 16 + 4 * h16 + r;      // s-local
          int col = wc * 64 + nf * 16 + l15;              // n-local
          *(u16*)((char*)sh + col * 256 + (((row >> 3) ^ (col & 7)) << 4) + (row & 7) * 2) =
              f2bf(acc[mf][nf][r]);
        }
    __syncthreads();
    int col = tid >> 1, half = tid & 1;
    int bb = m0 >> 11, s0 = (m0 & 2047) + half * 64;
    int nn = n0 - 2048 + col;
    int hh = nn >> 6, dv = nn & 63;
    u16* dst = o + ((size_t)(bb * NHEAD + hh) * 64 + dv) * S_LEN + s0;
    const char* base = (const char*)sh + col * 256;
#pragma unroll
    for (int i = 0; i < 8; ++i) {
      int ch = (half * 8 + i) ^ (col & 7);
      *(short8*)(dst + i * 8) = *(const short8*)(base + (ch << 4));
    }
  } else {
    float* o = (float*)out;
#pragma unroll
    for (int mf = 0; mf < 4; ++mf)
#pragma unroll
      for (int nf = 0; nf < 4; ++nf)
#pragma unroll
        for (int r = 0; r < 4; ++r) {
          int m = m0 + wr * 64 + mf * 16 + 4 * h16 + r;
          int n = n0 + wc * 64 + nf * 16 + l15;
          o[(size_t)m * 1024 + n] = acc[mf][nf][r];
        }
  }
}

// ---------------- attention staging helpers ----------------
__device__ __forceinline__ void stage_qk(const char* base, int row0, u16* dst, int tid) {
#pragma unroll
  for (int i = 0; i < 2; ++i) {
    int cid = i * 512 + tid;
    int row = cid >> 3, c = cid & 7;
    gload16(base + (size_t)(row0 + row) * 128 + ((c ^ (row & 7)) << 4),
            (char*)dst + i * 8192 + (tid & ~63) * 16);
  }
}
__device__ __forceinline__ void stage_v(const char* Vb, int kv0, u16* dst, int tid) {
#pragma unroll
  for (int i = 0; i < 2; ++i) {
    int cid = i * 512 + tid;
    int row = cid >> 4, c = cid & 15;
    gload16(Vb + (size_t)row * 4096 + (size_t)kv0 * 2 + ((c ^ (row & 7)) << 4),
            (char*)dst + i * 8192 + (tid & ~63) * 16);
  }
}

// ---------------- attn5: swapped QK (P in registers), one (qt,bh) ----------------
// sc[nf] = mfma(A=K rows, B=Q cols) -> C[col=q=w16+l15][row=kv=nf*16+4h16+r].
// attn store: lane-local f32x4 (4 contiguous kv for its q-row).
// PV: O^T = mfma(A=vT rows dv, B=P-frag); P-frag via R13-verified 8-shfl assembly.
__device__ __forceinline__ void attn5_one(
    const u16* __restrict__ Q, const u16* __restrict__ K, const u16* __restrict__ VT,
    float* __restrict__ attn, u16* __restrict__ ctx, int qt, int bh, int tid,
    u16 (*Ks)[128 * 64], u16* Vs) {
  const int lane = tid & 63, wv = tid >> 6;
  const int l15 = lane & 15, h16 = lane >> 4;
  const int w16 = wv * 16;
  const int q0 = qt * 128;
  const char* Kb = (const char*)(K + (size_t)bh * S_LEN * 64);
  const char* Vb = (const char*)(VT + (size_t)bh * 64 * S_LEN);
  float* attb = attn + (size_t)bh * S_LEN * S_LEN;

  // Q fragments direct from global (L2-hot, wave-local; B-operand cols = q)
  const u16* qrow = Q + (size_t)bh * S_LEN * 64 + (size_t)(q0 + w16 + l15) * 64 + h16 * 8;
  const short8 qf0 = *(const short8*)qrow;
  const short8 qf1 = *(const short8*)(qrow + 32);

  stage_qk(Kb, q0, Ks[0], tid);        // K[qt] (pass 1 runs descending)
  __syncthreads();

  // ---- pass 1: denominator (t = qt .. 0, K double-buffered) ----
  float lsum = 0.f;
  int cur = 0;
  for (int t = qt; t >= 0; --t) {
    if (t > 0) stage_qk(Kb, (t - 1) * 128, Ks[cur ^ 1], tid);
    const char* Kc = (const char*)Ks[cur];
#pragma unroll
    for (int nf = 0; nf < 8; ++nf) {
      int row = nf * 16 + l15;
      short8 k0 = *(const short8*)(Kc + row * 128 + ((h16 ^ (row & 7)) << 4));
      short8 k1 = *(const short8*)(Kc + row * 128 + (((4 + h16) ^ (row & 7)) << 4));
      f32x4 sc = {0.f, 0.f, 0.f, 0.f};
      sc = MFMA16(k0, qf0, sc);
      sc = MFMA16(k1, qf1, sc);
      if (t == qt) {
#pragma unroll
        for (int r = 0; r < 4; ++r)
          if (nf * 16 + 4 * h16 + r > w16 + l15) sc[r] = -1e30f;
      }
#pragma unroll
      for (int r = 0; r < 4; ++r) lsum += __expf(sc[r]);
    }
    __syncthreads();
    cur ^= 1;
  }
  cur ^= 1;                            // Ks[cur] holds K tile t=0
  lsum += __shfl_xor(lsum, 16);
  lsum += __shfl_xor(lsum, 32);
  const float ri = 1.0f / lsum;

  // ---- pass 2: emit (t = 0 .. qt) ----
  f32x4 acc[4];
#pragma unroll
  for (int i = 0; i < 4; ++i) acc[i] = (f32x4){0.f, 0.f, 0.f, 0.f};

  for (int t = 0; t <= qt; ++t) {
    const int kv0 = t * 128;
    stage_v(Vb, kv0, Vs, tid);         // in flight during QK phase
    const char* Kc = (const char*)Ks[cur];
    uint32_t pk[16];
    float* arow = attb + (size_t)(q0 + w16 + l15) * S_LEN + kv0 + 4 * h16;
#pragma unroll
    for (int nf = 0; nf < 8; ++nf) {
      int row = nf * 16 + l15;
      short8 k0 = *(const short8*)(Kc + row * 128 + ((h16 ^ (row & 7)) << 4));
      short8 k1 = *(const short8*)(Kc + row * 128 + (((4 + h16) ^ (row & 7)) << 4));
      f32x4 sc = {0.f, 0.f, 0.f, 0.f};
      sc = MFMA16(k0, qf0, sc);
      sc = MFMA16(k1, qf1, sc);
      if (t == qt) {
#pragma unroll
        for (int r = 0; r < 4; ++r)
          if (nf * 16 + 4 * h16 + r > w16 + l15) sc[r] = -1e30f;
      }
      f32x4 pr;
#pragma unroll
      for (int r = 0; r < 4; ++r) pr[r] = __expf(sc[r]) * ri;
      *(f32x4*)(arow + nf * 16) = pr;  // direct f32 attn store (16B, lane-local kv run)
      pk[2 * nf] = (uint32_t)f2bf(pr[0]) | ((uint32_t)f2bf(pr[1]) << 16);
      pk[2 * nf + 1] = (uint32_t)f2bf(pr[2]) | ((uint32_t)f2bf(pr[3]) << 16);
    }
    __syncthreads();                   // V[t] arrived, Ks[cur] reads done, stores drained
    if (t < qt) stage_qk(Kb, kv0 + 128, Ks[cur ^ 1], tid);  // in flight during PV
    // PV: per 32-kv chunk assemble P B-frag from pk via shfl (R13-verified pattern)
    const int lo = ((h16 & 1) << 5) + l15;
    const int hi = lo + 16;
    const bool tB = (h16 >= 2);
#pragma unroll
    for (int ks = 0; ks < 4; ++ks) {
      uint32_t a0 = (uint32_t)__shfl((int)pk[4 * ks + 0], lo);
      uint32_t a1 = (uint32_t)__shfl((int)pk[4 * ks + 1], lo);
      uint32_t a2 = (uint32_t)__shfl((int)pk[4 * ks + 0], hi);
      uint32_t a3 = (uint32_t)__shfl((int)pk[4 * ks + 1], hi);
      uint32_t b0 = (uint32_t)__shfl((int)pk[4 * ks + 2], lo);
      uint32_t b1 = (uint32_t)__shfl((int)pk[4 * ks + 3], lo);
      uint32_t b2 = (uint32_t)__shfl((int)pk[4 * ks + 2], hi);
      uint32_t b3 = (uint32_t)__shfl((int)pk[4 * ks + 3], hi);
      union { uint32_t u[4]; short8 s8; } pf;
      pf.u[0] = tB ? b0 : a0;
      pf.u[1] = tB ? b1 : a1;
      pf.u[2] = tB ? b2 : a2;
      pf.u[3] = tB ? b3 : a3;
#pragma unroll
      for (int dvt = 0; dvt < 4; ++dvt) {
        int rowV = dvt * 16 + l15;
        short8 vf = *(const short8*)((const char*)Vs + rowV * 256 + (((ks * 4 + h16) ^ (rowV & 7)) << 4));
        acc[dvt] = MFMA16(vf, pf.s8, acc[dvt]);
      }
    }
    __syncthreads();                   // Vs reuse next iter; K[t+1] drained
    cur ^= 1;
  }

  // upper-triangle tiles are exactly zero
  for (int kvt = qt + 1; kvt < 16; ++kvt) {
    const int kv0 = kvt * 128;
    int row = tid >> 2, sub = tid & 3;
    float* az = attb + (size_t)(q0 + row) * S_LEN + kv0;
    f32x4 z = {0.f, 0.f, 0.f, 0.f};
#pragma unroll
    for (int c8 = 0; c8 < 4; ++c8) {
      int chunk = sub + 4 * c8;
      *(f32x4*)(az + chunk * 8) = z;
      *(f32x4*)(az + chunk * 8 + 4) = z;
    }
  }

  // ctx store: acc C layout col=q(=w16+l15), row=dv(4h16+r)
  {
    int b = bh >> 4, hh = bh & 15;
    u16* crow = ctx + ((size_t)b * S_LEN + q0 + w16 + l15) * 1024 + hh * 64;
#pragma unroll
    for (int dvt = 0; dvt < 4; ++dvt)
#pragma unroll
      for (int r = 0; r < 4; ++r)
        crow[dvt * 16 + 4 * h16 + r] = f2bf(acc[dvt][r]);
  }
}

// 1-D grid 512, XCD-clustered (bh%8 = wgid%8). LDS 48KB + VGPR<=85 -> 3 blocks/CU.
__global__ __launch_bounds__(512, 6) void attn5_kernel(
    const u16* __restrict__ Q, const u16* __restrict__ K, const u16* __restrict__ VT,
    float* __restrict__ attn, u16* __restrict__ ctx) {
  __shared__ u16 Ks[2][128 * 64];
  __shared__ u16 Vs[64 * 128];
  const int tid = threadIdx.x;
  const int w = blockIdx.x;
  const int bx = (w >> 3) & 7;
  const int bh = (w & 7) + ((w >> 6) << 3);
  attn5_one(Q, K, VT, attn, ctx, 15 - bx, bh, tid, Ks, Vs);
  attn5_one(Q, K, VT, attn, ctx, bx, bh, tid, Ks, Vs);
}

// ---------------- residual + layernorm (in-place on proj) ----------------
__global__ __launch_bounds__(256) void ln_kernel(float* __restrict__ io,
                                                 const float* __restrict__ x,
                                                 const float* __restrict__ gamma,
                                                 const float* __restrict__ beta) {
  int row = blockIdx.x, tid = threadIdx.x;
  size_t base = (size_t)row * 1024 + tid * 4;
  f32x4 p = *(const f32x4*)(io + base);
  f32x4 xv = *(const f32x4*)(x + base);
  f32x4 y;
  float s1 = 0.f, s2 = 0.f;
#pragma unroll
  for (int j = 0; j < 4; ++j) {
    y[j] = p[j] + xv[j];
    s1 += y[j];
    s2 += y[j] * y[j];
  }
#pragma unroll
  for (int off = 1; off <= 32; off <<= 1) {
    s1 += __shfl_xor(s1, off);
    s2 += __shfl_xor(s2, off);
  }
  __shared__ float r1[4], r2[4];
  int w = tid >> 6;
  if ((tid & 63) == 0) { r1[w] = s1; r2[w] = s2; }
  __syncthreads();
  float S1 = r1[0] + r1[1] + r1[2] + r1[3];
  float S2 = r2[0] + r2[1] + r2[2] + r2[3];
  float mu = S1 * (1.f / 1024.f);
  float var = S2 * (1.f / 1024.f) - mu * mu;
  float rs = rsqrtf(var + 1e-5f);
  f32x4 g = *(const f32x4*)(gamma + tid * 4);
  f32x4 bt = *(const f32x4*)(beta + tid * 4);
  f32x4 o;
#pragma unroll
  for (int j = 0; j < 4; ++j) o[j] = (y[j] - mu) * rs * g[j] + bt[j];
  *(f32x4*)(io + base) = o;
}

extern "C" void kernel_launch(void* const* d_in, const int* in_sizes, int n_in,
                              void* d_out, int out_size, void* d_ws, size_t ws_size,
                              hipStream_t stream) {
  (void)in_sizes; (void)n_in; (void)out_size; (void)ws_size;
  const float* x = (const float*)d_in[0];
  // d_in[1] = attention_mask: deterministic causal, applied analytically, never read.
  const float* wq = (const float*)d_in[2];
  const float* wk = (const float*)d_in[3];
  const float* wv = (const float*)d_in[4];
  const float* wfc = (const float*)d_in[5];
  const float* gamma = (const float*)d_in[6];
  const float* beta = (const float*)d_in[7];

  char* ws = (char*)d_ws;
  u16* xb = (u16*)ws;                       // 0..16 MiB; dead after QKV -> reused as ctx
  u16* wqkvT = (u16*)(ws + (16u << 20));    // 6 MiB (3072 x 1024)
  u16* wfcT = (u16*)(ws + (22u << 20));     // 2 MiB
  u16* qkb = (u16*)(ws + (24u << 20));      // 32 MiB: q @24, k @40 (b,h,s,64)
  u16* qb = qkb;
  u16* kb = qkb + (size_t)8388608;
  u16* vT = (u16*)(ws + (56u << 20));       // 16 MiB (B,H,64,S)
  u16* ctx = xb;

  float* outp = (float*)d_out;                            // 4*2048*1024 f32
  float* attnp = outp + (size_t)4 * 2048 * 1024;          // 4*16*2048*2048 f32

  prep_kernel<<<12288, 256, 0, stream>>>(x, xb, wq, wk, wv, wfc, wqkvT, wfcT);
  gemm_bt_kernel<<<dim3(64, 24), 256, 0, stream>>>(xb, wqkvT, qkb, vT, 0);
  attn5_kernel<<<512, 512, 0, stream>>>(qb, kb, vT, attnp, ctx);
  gemm_bt_kernel<<<dim3(64, 8), 256, 0, stream>>>(ctx, wfcT, outp, nullptr, 1);
  ln_kernel<<<8192, 256, 0, stream>>>(outp, x, gamma, beta);
}

// Round 17
// 470.627 us; speedup vs baseline: 3.5982x; 1.1623x over previous
//
#include <hip/hip_runtime.h>
#include <stdint.h>

#define S_LEN 2048
#define NHEAD 16

typedef short short8 __attribute__((ext_vector_type(8)));
typedef float f32x4 __attribute__((ext_vector_type(4)));
typedef unsigned short u16;

typedef __attribute__((address_space(1))) uint32_t AS1u32;
typedef __attribute__((address_space(3))) uint32_t AS3u32;

#define MFMA16(a, b, c) __builtin_amdgcn_mfma_f32_16x16x32_bf16((a), (b), (c), 0, 0, 0)

__device__ __forceinline__ void gload16(const void* g, void* l) {
  __builtin_amdgcn_global_load_lds((AS1u32*)g, (AS3u32*)l, 16, 0, 0);
}

__device__ __forceinline__ u16 f2bf(float f) {
  union { float f; uint32_t u; } c; c.f = f;
  return (u16)((c.u + 0x7fffu + ((c.u >> 16) & 1u)) >> 16);
}

// ---------------- prep: x -> bf16  +  weights -> bf16 transposed ----------------
__global__ __launch_bounds__(256) void prep_kernel(
    const float* __restrict__ x, u16* __restrict__ xb,
    const float* __restrict__ w0, const float* __restrict__ w1,
    const float* __restrict__ w2, const float* __restrict__ w3,
    u16* __restrict__ qkvT, u16* __restrict__ fcT) {
  __shared__ float t[32][33];
  int bid = blockIdx.x;
  if (bid < 8192) {
    size_t i = ((size_t)bid * 256 + threadIdx.x) * 4;
    f32x4 v = *(const f32x4*)(x + i);
    union { u16 h[4]; uint2 d; } o;
    o.h[0] = f2bf(v[0]); o.h[1] = f2bf(v[1]); o.h[2] = f2bf(v[2]); o.h[3] = f2bf(v[3]);
    *(uint2*)(xb + i) = o.d;
    return;
  }
  int r = bid - 8192;
  int z = r >> 10; r &= 1023;
  int bx = r & 31, by = r >> 5;
  const float* w = (z == 0) ? w0 : (z == 1) ? w1 : (z == 2) ? w2 : w3;
  u16* o = (z == 3) ? fcT : qkvT + (size_t)z * 1048576;
  float scale = (z == 0) ? 0.125f : 1.0f;
  int n0 = bx * 32, k0 = by * 32;
  int tx = threadIdx.x & 31, ty = threadIdx.x >> 5;
#pragma unroll
  for (int i = 0; i < 4; ++i) {
    int k = ty * 4 + i;
    t[k][tx] = w[(size_t)(k0 + k) * 1024 + n0 + tx];
  }
  __syncthreads();
#pragma unroll
  for (int i = 0; i < 4; ++i) {
    int n = ty * 4 + i;
    o[(size_t)(n0 + n) * 1024 + k0 + tx] = f2bf(t[tx][n] * scale);
  }
}

// ---------------- 128x128x(K=1024) bf16 GEMM, C = A * BT^T ----------------
__device__ __forceinline__ void gemm_stage(const char* Ab, const char* Bb, u16* As, u16* Bs,
                                           int m0, int n0, int kbyte, int tid) {
#pragma unroll
  for (int i = 0; i < 2; ++i) {
    int cid = i * 256 + tid;
    int row = cid >> 2, c = cid & 3;
    int off = kbyte + ((c ^ ((row >> 1) & 3)) << 4);
    gload16(Ab + (size_t)(m0 + row) * 2048 + off, (char*)As + i * 4096 + (tid & ~63) * 16);
    gload16(Bb + (size_t)(n0 + row) * 2048 + off, (char*)Bs + i * 4096 + (tid & ~63) * 16);
  }
}

__global__ __launch_bounds__(256) void gemm_bt_kernel(
    const u16* __restrict__ A, const u16* __restrict__ BT,
    void* __restrict__ out, void* __restrict__ outv, int mode) {
  __shared__ u16 sh[128 * 128];
  u16* As = sh;
  u16* Bs = sh + 4096;
  const int tid = threadIdx.x;
  const int lane = tid & 63, wv = tid >> 6;
  const int l15 = lane & 15, h16 = lane >> 4;
  const int wr = wv >> 1, wc = wv & 1;
  const int m0 = blockIdx.x * 128, n0 = blockIdx.y * 128;
  const char* Ab = (const char*)A;
  const char* Bb = (const char*)BT;

  f32x4 acc[4][4];
#pragma unroll
  for (int i = 0; i < 4; ++i)
#pragma unroll
    for (int j = 0; j < 4; ++j) acc[i][j] = (f32x4){0.f, 0.f, 0.f, 0.f};

  gemm_stage(Ab, Bb, As, Bs, m0, n0, 0, tid);
  for (int kt = 0; kt < 32; ++kt) {
    __syncthreads();
    short8 a[4], b[4];
#pragma unroll
    for (int mf = 0; mf < 4; ++mf) {
      int row = wr * 64 + mf * 16 + l15;
      a[mf] = *(const short8*)((const char*)As + row * 64 + ((h16 ^ ((row >> 1) & 3)) << 4));
    }
#pragma unroll
    for (int nf = 0; nf < 4; ++nf) {
      int row = wc * 64 + nf * 16 + l15;
      b[nf] = *(const short8*)((const char*)Bs + row * 64 + ((h16 ^ ((row >> 1) & 3)) << 4));
    }
#pragma unroll
    for (int mf = 0; mf < 4; ++mf)
#pragma unroll
      for (int nf = 0; nf < 4; ++nf)
        acc[mf][nf] = MFMA16(a[mf], b[nf], acc[mf][nf]);
    __syncthreads();
    if (kt + 1 < 32) gemm_stage(Ab, Bb, As, Bs, m0, n0, (kt + 1) * 64, tid);
  }

  if (mode == 0 && n0 < 2048) {
    u16* o = (u16*)out;
#pragma unroll
    for (int mf = 0; mf < 4; ++mf)
#pragma unroll
      for (int nf = 0; nf < 4; ++nf)
#pragma unroll
        for (int r = 0; r < 4; ++r) {
          int row = wr * 64 + mf * 16 + 4 * h16 + r;
          int col = wc * 64 + nf * 16 + l15;
          *(u16*)((char*)sh + row * 256 + (((col >> 3) ^ (row & 7)) << 4) + (col & 7) * 2) =
              f2bf(acc[mf][nf][r]);
        }
    __syncthreads();
    int row = tid >> 1, hf = tid & 1;
    int m = m0 + row;
    int bb = m >> 11, s = m & 2047;
    int n_base = n0 + hf * 64;
    int z = n_base >> 10, nn = n_base & 1023, hh = nn >> 6;
    u16* dst = o + (size_t)z * 8388608 + (((size_t)(bb * NHEAD + hh) * S_LEN + s) << 6);
#pragma unroll
    for (int i = 0; i < 8; ++i) {
      int ch = hf * 8 + i;
      short8 v = *(const short8*)((const char*)sh + row * 256 + ((ch ^ (row & 7)) << 4));
      *(short8*)(dst + i * 8) = v;
    }
  } else if (mode == 0) {
    u16* o = (u16*)outv;
#pragma unroll
    for (int mf = 0; mf < 4; ++mf)
#pragma unroll
      for (int nf = 0; nf < 4; ++nf)
#pragma unroll
        for (int r = 0; r < 4; ++r) {
          int row = wr * 64 + mf * 16 + 4 * h16 + r;      // s-local
          int col = wc * 64 + nf * 16 + l15;              // n-local
          *(u16*)((char*)sh + col * 256 + (((row >> 3) ^ (col & 7)) << 4) + (row & 7) * 2) =
              f2bf(acc[mf][nf][r]);
        }
    __syncthreads();
    int col = tid >> 1, half = tid & 1;
    int bb = m0 >> 11, s0 = (m0 & 2047) + half * 64;
    int nn = n0 - 2048 + col;
    int hh = nn >> 6, dv = nn & 63;
    u16* dst = o + ((size_t)(bb * NHEAD + hh) * 64 + dv) * S_LEN + s0;
    const char* base = (const char*)sh + col * 256;
#pragma unroll
    for (int i = 0; i < 8; ++i) {
      int ch = (half * 8 + i) ^ (col & 7);
      *(short8*)(dst + i * 8) = *(const short8*)(base + (ch << 4));
    }
  } else {
    float* o = (float*)out;
#pragma unroll
    for (int mf = 0; mf < 4; ++mf)
#pragma unroll
      for (int nf = 0; nf < 4; ++nf)
#pragma unroll
        for (int r = 0; r < 4; ++r) {
          int m = m0 + wr * 64 + mf * 16 + 4 * h16 + r;
          int n = n0 + wc * 64 + nf * 16 + l15;
          o[(size_t)m * 1024 + n] = acc[mf][nf][r];
        }
  }
}

// ---------------- attention staging helpers ----------------
__device__ __forceinline__ void stage_qk(const char* base, int row0, u16* dst, int tid) {
#pragma unroll
  for (int i = 0; i < 2; ++i) {
    int cid = i * 512 + tid;
    int row = cid >> 3, c = cid & 7;
    gload16(base + (size_t)(row0 + row) * 128 + ((c ^ (row & 7)) << 4),
            (char*)dst + i * 8192 + (tid & ~63) * 16);
  }
}
__device__ __forceinline__ void stage_v(const char* Vb, int kv0, u16* dst, int tid) {
#pragma unroll
  for (int i = 0; i < 2; ++i) {
    int cid = i * 512 + tid;
    int row = cid >> 4, c = cid & 15;
    gload16(Vb + (size_t)row * 4096 + (size_t)kv0 * 2 + ((c ^ (row & 7)) << 4),
            (char*)dst + i * 8192 + (tid & ~63) * 16);
  }
}

__device__ __forceinline__ void qk_tile(const char* Kc, const short8* qf,
                                        f32x4* sc, int l15, int h16) {
#pragma unroll
  for (int nf = 0; nf < 8; ++nf) sc[nf] = (f32x4){0.f, 0.f, 0.f, 0.f};
#pragma unroll
  for (int ks = 0; ks < 2; ++ks)
#pragma unroll
    for (int nf = 0; nf < 8; ++nf) {
      int row = nf * 16 + l15;
      short8 kb = *(const short8*)(Kc + row * 128 + (((ks * 4 + h16) ^ (row & 7)) << 4));
      sc[nf] = MFMA16(qf[ks], kb, sc[nf]);
    }
}

// ---------------- fused attention: denom prologue + emit, one (qt,bh) ----------------
__device__ __forceinline__ void attn_one(
    const u16* __restrict__ Q, const u16* __restrict__ K, const u16* __restrict__ VT,
    float* __restrict__ attn, u16* __restrict__ ctx, int qt, int bh, int tid,
    u16 (*Ks)[128 * 64], u16* Vs, u16* Ps) {
  const int lane = tid & 63, wv = tid >> 6;
  const int l15 = lane & 15, h16 = lane >> 4;
  const int w16 = wv * 16;
  const int q0 = qt * 128;
  const char* Qb = (const char*)(Q + (size_t)bh * S_LEN * 64);
  const char* Kb = (const char*)(K + (size_t)bh * S_LEN * 64);
  const char* Vb = (const char*)(VT + (size_t)bh * 64 * S_LEN);
  float* attb = attn + (size_t)bh * S_LEN * S_LEN;

  stage_qk(Qb, q0, Ps, tid);           // Q parked in Ps region
  stage_qk(Kb, q0, Ks[0], tid);        // K[qt] (pass 1 runs descending)
  __syncthreads();
  short8 qf[2];
  {
    int row = w16 + l15;
    qf[0] = *(const short8*)((const char*)Ps + row * 128 + ((h16 ^ (row & 7)) << 4));
    qf[1] = *(const short8*)((const char*)Ps + row * 128 + (((4 + h16) ^ (row & 7)) << 4));
  }
  __syncthreads();

  // ---- pass 1: denominators (t = qt .. 0, K double-buffered) ----
  float lsum[4] = {0.f, 0.f, 0.f, 0.f};
  int cur = 0;
  for (int t = qt; t >= 0; --t) {
    if (t > 0) stage_qk(Kb, (t - 1) * 128, Ks[cur ^ 1], tid);
    f32x4 sc[8];
    qk_tile((const char*)Ks[cur], qf, sc, l15, h16);
    if (t == qt) {
#pragma unroll
      for (int nf = 0; nf < 8; ++nf)
#pragma unroll
        for (int r = 0; r < 4; ++r)
          if (nf * 16 + l15 > w16 + 4 * h16 + r) sc[nf][r] = -1e30f;
    }
#pragma unroll
    for (int nf = 0; nf < 8; ++nf)
#pragma unroll
      for (int r = 0; r < 4; ++r) lsum[r] += __expf(sc[nf][r]);
    __syncthreads();
    cur ^= 1;
  }
  cur ^= 1;                            // Ks[cur] holds K tile t=0
  f32x4 ri;
#pragma unroll
  for (int r = 0; r < 4; ++r) {
    float v = lsum[r];
    v += __shfl_xor(v, 1);
    v += __shfl_xor(v, 2);
    v += __shfl_xor(v, 4);
    v += __shfl_xor(v, 8);
    ri[r] = 1.0f / v;
  }

  // ---- pass 2: emit (t = 0 .. qt) ----
  f32x4 cacc[4];
#pragma unroll
  for (int nf = 0; nf < 4; ++nf) cacc[nf] = (f32x4){0.f, 0.f, 0.f, 0.f};

  for (int t = 0; t <= qt; ++t) {
    const int kv0 = t * 128;
    stage_v(Vb, kv0, Vs, tid);         // in flight during QK phase
    f32x4 sc[8];
    qk_tile((const char*)Ks[cur], qf, sc, l15, h16);
    if (t == qt) {
#pragma unroll
      for (int nf = 0; nf < 8; ++nf)
#pragma unroll
        for (int r = 0; r < 4; ++r)
          if (nf * 16 + l15 > w16 + 4 * h16 + r) sc[nf][r] = -1e30f;
    }
    // exp -> P(bf16) to LDS for PV, and DIRECT f32 attn store from registers.
    {
      float* arow = attb + (size_t)(q0 + w16 + 4 * h16) * S_LEN + kv0 + l15;
#pragma unroll
      for (int nf = 0; nf < 8; ++nf)
#pragma unroll
        for (int r = 0; r < 4; ++r) {
          float p = __expf(sc[nf][r]) * ri[r];
          int rowL = w16 + 4 * h16 + r;
          int chunk = 2 * nf + (l15 >> 3);
          *(u16*)((char*)Ps + rowL * 256 + ((chunk ^ (rowL & 7)) << 4) + (l15 & 7) * 2) = f2bf(p);
          arow[(size_t)r * S_LEN + nf * 16] = p;
        }
    }
    __syncthreads();                   // V[t] ready, P visible (attn stores drain to L2)
    if (t < qt) stage_qk(Kb, kv0 + 128, Ks[cur ^ 1], tid);  // in flight during PV
    // PV
#pragma unroll
    for (int ks = 0; ks < 4; ++ks) {
      int rowP = w16 + l15;
      short8 pa = *(const short8*)((const char*)Ps + rowP * 256 + (((ks * 4 + h16) ^ (rowP & 7)) << 4));
#pragma unroll
      for (int nf = 0; nf < 4; ++nf) {
        int rowV = nf * 16 + l15;
        short8 vbf = *(const short8*)((const char*)Vs + rowV * 256 + (((ks * 4 + h16) ^ (rowV & 7)) << 4));
        cacc[nf] = MFMA16(pa, vbf, cacc[nf]);
      }
    }
    __syncthreads();                   // Ps/Vs reuse; K[t+1] drained
    cur ^= 1;
  }

  // upper-triangle tiles are exactly zero
  for (int kvt = qt + 1; kvt < 16; ++kvt) {
    const int kv0 = kvt * 128;
    int row = tid >> 2, sub = tid & 3;
    float* arow = attb + (size_t)(q0 + row) * S_LEN + kv0;
    f32x4 z = {0.f, 0.f, 0.f, 0.f};
#pragma unroll
    for (int c8 = 0; c8 < 4; ++c8) {
      int chunk = sub + 4 * c8;
      *(f32x4*)(arow + chunk * 8) = z;
      *(f32x4*)(arow + chunk * 8 + 4) = z;
    }
  }

  // context store (B*S, H*64) bf16
  {
    int b = bh >> 4, hh = bh & 15;
#pragma unroll
    for (int nf = 0; nf < 4; ++nf)
#pragma unroll
      for (int r = 0; r < 4; ++r) {
        int qrow = q0 + w16 + 4 * h16 + r;
        ctx[((size_t)b * S_LEN + qrow) * 1024 + hh * 64 + nf * 16 + l15] = f2bf(cacc[nf][r]);
      }
  }
}

// 1-D grid 512, XCD-clustered: xcd = wgid%8 == bh%8 -> all 8 blocks of a bh share an L2
// (K/V working set of 8 bh = 4 MB = one XCD L2). Heavy+light qt pair per block.
__global__ __launch_bounds__(512) void attn2_kernel(
    const u16* __restrict__ Q, const u16* __restrict__ K, const u16* __restrict__ VT,
    float* __restrict__ attn, u16* __restrict__ ctx) {
  __shared__ u16 Ks[2][128 * 64];
  __shared__ u16 Vs[64 * 128];
  __shared__ u16 Ps[128 * 128];
  const int tid = threadIdx.x;
  const int w = blockIdx.x;
  const int bx = (w >> 3) & 7;
  const int bh = (w & 7) + ((w >> 6) << 3);
  attn_one(Q, K, VT, attn, ctx, 15 - bx, bh, tid, Ks, Vs, Ps);
  attn_one(Q, K, VT, attn, ctx, bx, bh, tid, Ks, Vs, Ps);
}

// ---------------- residual + layernorm (in-place on proj) ----------------
__global__ __launch_bounds__(256) void ln_kernel(float* __restrict__ io,
                                                 const float* __restrict__ x,
                                                 const float* __restrict__ gamma,
                                                 const float* __restrict__ beta) {
  int row = blockIdx.x, tid = threadIdx.x;
  size_t base = (size_t)row * 1024 + tid * 4;
  f32x4 p = *(const f32x4*)(io + base);
  f32x4 xv = *(const f32x4*)(x + base);
  f32x4 y;
  float s1 = 0.f, s2 = 0.f;
#pragma unroll
  for (int j = 0; j < 4; ++j) {
    y[j] = p[j] + xv[j];
    s1 += y[j];
    s2 += y[j] * y[j];
  }
#pragma unroll
  for (int off = 1; off <= 32; off <<= 1) {
    s1 += __shfl_xor(s1, off);
    s2 += __shfl_xor(s2, off);
  }
  __shared__ float r1[4], r2[4];
  int w = tid >> 6;
  if ((tid & 63) == 0) { r1[w] = s1; r2[w] = s2; }
  __syncthreads();
  float S1 = r1[0] + r1[1] + r1[2] + r1[3];
  float S2 = r2[0] + r2[1] + r2[2] + r2[3];
  float mu = S1 * (1.f / 1024.f);
  float var = S2 * (1.f / 1024.f) - mu * mu;
  float rs = rsqrtf(var + 1e-5f);
  f32x4 g = *(const f32x4*)(gamma + tid * 4);
  f32x4 bt = *(const f32x4*)(beta + tid * 4);
  f32x4 o;
#pragma unroll
  for (int j = 0; j < 4; ++j) o[j] = (y[j] - mu) * rs * g[j] + bt[j];
  *(f32x4*)(io + base) = o;
}

extern "C" void kernel_launch(void* const* d_in, const int* in_sizes, int n_in,
                              void* d_out, int out_size, void* d_ws, size_t ws_size,
                              hipStream_t stream) {
  (void)in_sizes; (void)n_in; (void)out_size; (void)ws_size;
  const float* x = (const float*)d_in[0];
  // d_in[1] = attention_mask: deterministic causal, applied analytically, never read.
  const float* wq = (const float*)d_in[2];
  const float* wk = (const float*)d_in[3];
  const float* wv = (const float*)d_in[4];
  const float* wfc = (const float*)d_in[5];
  const float* gamma = (const float*)d_in[6];
  const float* beta = (const float*)d_in[7];

  char* ws = (char*)d_ws;
  u16* xb = (u16*)ws;
  u16* wqkvT = (u16*)(ws + (16u << 20));
  u16* wfcT = (u16*)(ws + (22u << 20));
  u16* qkb = (u16*)(ws + (24u << 20));
  u16* qb = qkb;
  u16* kb = qkb + (size_t)8388608;
  u16* vT = (u16*)(ws + (56u << 20));
  u16* ctx = xb;

  float* outp = (float*)d_out;
  float* attnp = outp + (size_t)4 * 2048 * 1024;

  prep_kernel<<<12288, 256, 0, stream>>>(x, xb, wq, wk, wv, wfc, wqkvT, wfcT);
  gemm_bt_kernel<<<dim3(64, 24), 256, 0, stream>>>(xb, wqkvT, qkb, vT, 0);
  attn2_kernel<<<512, 512, 0, stream>>>(qb, kb, vT, attnp, ctx);
  gemm_bt_kernel<<<dim3(64, 8), 256, 0, stream>>>(ctx, wfcT, outp, nullptr, 1);
  ln_kernel<<<8192, 256, 0, stream>>>(outp, x, gamma, beta);
}